// Round 1
// baseline (12970.142 us; speedup 1.0000x reference)
//
#include <hip/hip_runtime.h>
#include <hip/hip_bf16.h>
#include <math.h>

typedef _Float16 f16x8 __attribute__((ext_vector_type(8)));
typedef float    f32x4 __attribute__((ext_vector_type(4)));

#define DEV __device__ __forceinline__

static constexpr int Ee   = 300;   // glove dim
static constexpr int INP  = 303;   // E + 3
static constexpr int INPP = 320;   // padded input dim
static constexpr int Hh   = 512;
static constexpr int Bb   = 64;
static constexpr int Tt   = 512;
static constexpr int D2H  = 1024;  // 2H

// ---- MFMA fragment load: K-major matrix M[row][k], frag[l][j] = M[row0+(l&15)][k0+8*(l>>4)+j]
DEV f16x8 ldfrag(const _Float16* base, int ld, int row0, int k0, int lane) {
  return *reinterpret_cast<const f16x8*>(base + (size_t)(row0 + (lane & 15)) * ld + (k0 + 8 * (lane >> 4)));
}
DEV float sigm(float x) { return 1.0f / (1.0f + expf(-x)); }

// ---------------- weight convert (f32 -> f16, optional column pad) ----------------
__global__ void convert_pad(const float* __restrict__ src, _Float16* __restrict__ dst,
                            int rows, int csrc, int cdst) {
  int i = blockIdx.x * 256 + threadIdx.x;
  if (i >= rows * cdst) return;
  int r = i / cdst, c = i - r * cdst;
  dst[i] = (c < csrc) ? (_Float16)src[(size_t)r * csrc + c] : (_Float16)0.0f;
}

// ---------------- embedding: xt (T, B, INPP) f16 ----------------
__global__ void embed_kernel(const int* __restrict__ context, const int* __restrict__ tags,
                             const float* __restrict__ glove, const float* __restrict__ bio,
                             _Float16* __restrict__ xt) {
  int blk = blockIdx.x;            // t*64 + b
  int t = blk >> 6, b = blk & 63;
  int cid = context[b * Tt + t];   // context (B,T,1)
  int tag = tags[b * Tt + t];      // (B,T)
  _Float16* dst = xt + (size_t)blk * INPP;
  for (int c = threadIdx.x; c < INPP; c += 64) {
    float v = (c < Ee) ? glove[(size_t)cid * Ee + c]
                       : ((c < INP) ? bio[tag * 3 + (c - Ee)] : 0.0f);
    dst[c] = (_Float16)v;
  }
}

// ---------------- GRU pipelined step ----------------
struct GruParams {
  const _Float16* xt;
  const _Float16* Wx[2][2];   // [dir][layer] input-side weights (ld = 320 or 512)
  const _Float16* Wh[2][2];   // hidden-side weights (ld = 512)
  const float* bih[2][2];
  const float* bhh[2][2];
  float*     h32[2][2];       // 2 slots x 64 x 512 each
  _Float16*  h16[2][2];
  _Float16*  allh;            // (B, T, 2H) f16
};

__global__ __launch_bounds__(256) void gru_step(GruParams P, int s) {
  int unit = blockIdx.x >> 5;         // 0:f-L1 1:b-L1 2:f-L2 3:b-L2
  int cb   = (blockIdx.x & 31) << 4;  // h-column base
  int layer = unit >> 1, dir = unit & 1;
  int t;
  if (layer == 0) { if (s >= Tt) return; t = s; }
  else            { if (s == 0)  return; t = s - 1; }

  const _Float16* xsrc; int ldx, Kx;
  if (layer == 0) {
    int tt = dir ? (Tt - 1 - t) : t;
    xsrc = P.xt + (size_t)tt * Bb * INPP; ldx = INPP; Kx = INPP;
  } else {
    xsrc = P.h16[dir][0] + (size_t)(t & 1) * (Bb * Hh); ldx = Hh; Kx = Hh;
  }
  const float*    hprev32 = P.h32[dir][layer] + (size_t)((t & 1) ^ 1) * (Bb * Hh);
  const _Float16* hprev16 = P.h16[dir][layer] + (size_t)((t & 1) ^ 1) * (Bb * Hh);
  float*    hout32 = P.h32[dir][layer] + (size_t)(t & 1) * (Bb * Hh);
  _Float16* hout16 = P.h16[dir][layer] + (size_t)(t & 1) * (Bb * Hh);

  int w = threadIdx.x >> 6, lane = threadIdx.x & 63;
  // wave roles: 0 -> r, 1 -> z, 2 -> n_i (x-side only), 3 -> n_h (h-side only)
  int nrow = ((w == 0) ? 0 : (w == 1) ? Hh : 2 * Hh) + cb;

  f32x4 a0 = {0.f,0.f,0.f,0.f}, a1 = a0, a2 = a0, a3 = a0;
  if (w != 3) {  // x-side
    const _Float16* Wx = P.Wx[dir][layer];
    for (int k0 = 0; k0 < Kx; k0 += 32) {
      f16x8 bfr = ldfrag(Wx, Kx, nrow, k0, lane);
      a0 = __builtin_amdgcn_mfma_f32_16x16x32_f16(ldfrag(xsrc, ldx,  0, k0, lane), bfr, a0, 0,0,0);
      a1 = __builtin_amdgcn_mfma_f32_16x16x32_f16(ldfrag(xsrc, ldx, 16, k0, lane), bfr, a1, 0,0,0);
      a2 = __builtin_amdgcn_mfma_f32_16x16x32_f16(ldfrag(xsrc, ldx, 32, k0, lane), bfr, a2, 0,0,0);
      a3 = __builtin_amdgcn_mfma_f32_16x16x32_f16(ldfrag(xsrc, ldx, 48, k0, lane), bfr, a3, 0,0,0);
    }
  }
  if (w != 2) {  // h-side
    const _Float16* Wh = P.Wh[dir][layer];
    for (int k0 = 0; k0 < Hh; k0 += 32) {
      f16x8 bfr = ldfrag(Wh, Hh, nrow, k0, lane);
      a0 = __builtin_amdgcn_mfma_f32_16x16x32_f16(ldfrag(hprev16, Hh,  0, k0, lane), bfr, a0, 0,0,0);
      a1 = __builtin_amdgcn_mfma_f32_16x16x32_f16(ldfrag(hprev16, Hh, 16, k0, lane), bfr, a1, 0,0,0);
      a2 = __builtin_amdgcn_mfma_f32_16x16x32_f16(ldfrag(hprev16, Hh, 32, k0, lane), bfr, a2, 0,0,0);
      a3 = __builtin_amdgcn_mfma_f32_16x16x32_f16(ldfrag(hprev16, Hh, 48, k0, lane), bfr, a3, 0,0,0);
    }
  }
  int col = lane & 15;
  const float* bih = P.bih[dir][layer];
  const float* bhh = P.bhh[dir][layer];
  float bv;
  if      (w == 0) bv = bih[cb + col] + bhh[cb + col];
  else if (w == 1) bv = bih[Hh + cb + col] + bhh[Hh + cb + col];
  else if (w == 2) bv = bih[2 * Hh + cb + col];
  else             bv = bhh[2 * Hh + cb + col];

  __shared__ float lds[4][64][16];
  int rbase = 4 * (lane >> 4);
  f32x4 acc[4] = {a0, a1, a2, a3};
#pragma unroll
  for (int mt = 0; mt < 4; ++mt)
#pragma unroll
    for (int r = 0; r < 4; ++r)
      lds[w][mt * 16 + rbase + r][col] = acc[mt][r] + bv;
  __syncthreads();

  for (int e = threadIdx.x; e < Bb * 16; e += 256) {
    int row = e >> 4, c = e & 15;
    float rr = sigm(lds[0][row][c]);
    float zz = sigm(lds[1][row][c]);
    float nn = tanhf(lds[2][row][c] + rr * lds[3][row][c]);
    float hp = hprev32[row * Hh + cb + c];
    float hv = (1.0f - zz) * nn + zz * hp;
    hout32[row * Hh + cb + c] = hv;
    _Float16 h6 = (_Float16)hv;
    hout16[row * Hh + cb + c] = h6;
    if (layer == 1)
      P.allh[((size_t)row * Tt + t) * D2H + dir * Hh + cb + c] = h6;
  }
}

// ---------------- generic TN GEMM: C = A(MxK) * B(NxK)^T (+bias) ----------------
struct GemmArgs {
  const _Float16* A; const _Float16* Bm;
  float* Cf; _Float16* Ch;
  const float* bias;
  int lda, ldb, ldc, K;
  long long sAz, sBz, sCz;
};

__global__ __launch_bounds__(256) void gemm_tn(GemmArgs g) {
  int z = blockIdx.z;
  const _Float16* A  = g.A  + (size_t)z * g.sAz;
  const _Float16* Bm = g.Bm + (size_t)z * g.sBz;
  int m0 = blockIdx.y * 64;
  int lane = threadIdx.x & 63;
  int n0 = blockIdx.x * 64 + (threadIdx.x >> 6) * 16;

  f32x4 a0 = {0.f,0.f,0.f,0.f}, a1 = a0, a2 = a0, a3 = a0;
  for (int k0 = 0; k0 < g.K; k0 += 32) {
    f16x8 bfr = ldfrag(Bm, g.ldb, n0, k0, lane);
    a0 = __builtin_amdgcn_mfma_f32_16x16x32_f16(ldfrag(A, g.lda, m0 +  0, k0, lane), bfr, a0, 0,0,0);
    a1 = __builtin_amdgcn_mfma_f32_16x16x32_f16(ldfrag(A, g.lda, m0 + 16, k0, lane), bfr, a1, 0,0,0);
    a2 = __builtin_amdgcn_mfma_f32_16x16x32_f16(ldfrag(A, g.lda, m0 + 32, k0, lane), bfr, a2, 0,0,0);
    a3 = __builtin_amdgcn_mfma_f32_16x16x32_f16(ldfrag(A, g.lda, m0 + 48, k0, lane), bfr, a3, 0,0,0);
  }
  int col = n0 + (lane & 15);
  float bv = g.bias ? g.bias[col] : 0.0f;
  int rbase = 4 * (lane >> 4);
  f32x4 acc[4] = {a0, a1, a2, a3};
#pragma unroll
  for (int mt = 0; mt < 4; ++mt)
#pragma unroll
    for (int r = 0; r < 4; ++r) {
      int row = m0 + mt * 16 + rbase + r;
      float v = acc[mt][r] + bv;
      size_t idx = (size_t)z * g.sCz + (size_t)row * g.ldc + col;
      if (g.Cf) g.Cf[idx] = v; else g.Ch[idx] = (_Float16)v;
    }
}

// ---------------- row softmax: scores f32 (.,512) -> p f16 ----------------
__global__ __launch_bounds__(256) void softmax_rows(const float* __restrict__ sc, _Float16* __restrict__ p) {
  int row = blockIdx.x * 4 + (threadIdx.x >> 6);
  int lane = threadIdx.x & 63;
  const float* s = sc + (size_t)row * 512 + lane * 8;
  float v[8];
  float4 q0 = *(const float4*)s, q1 = *(const float4*)(s + 4);
  v[0]=q0.x; v[1]=q0.y; v[2]=q0.z; v[3]=q0.w; v[4]=q1.x; v[5]=q1.y; v[6]=q1.z; v[7]=q1.w;
  float mx = v[0];
#pragma unroll
  for (int j = 1; j < 8; ++j) mx = fmaxf(mx, v[j]);
  for (int o = 32; o; o >>= 1) mx = fmaxf(mx, __shfl_xor(mx, o));
  float sum = 0.f;
#pragma unroll
  for (int j = 0; j < 8; ++j) { v[j] = expf(v[j] - mx); sum += v[j]; }
  for (int o = 32; o; o >>= 1) sum += __shfl_xor(sum, o);
  float inv = 1.0f / sum;
  _Float16* pd = p + (size_t)row * 512 + lane * 8;
#pragma unroll
  for (int j = 0; j < 8; ++j) pd[j] = (_Float16)(v[j] * inv);
}

// ---------------- per-batch transpose: allhT[b][d][t] = allh[b][t][d] ----------------
__global__ void transpose_bt(const _Float16* __restrict__ allh, _Float16* __restrict__ allhT) {
  __shared__ _Float16 tile[32][33];
  int b = blockIdx.z;
  int d0 = blockIdx.x * 32, t0 = blockIdx.y * 32;
  int tx = threadIdx.x, ty = threadIdx.y;  // (32, 8)
  const _Float16* in = allh + (size_t)b * Tt * D2H;
  _Float16* outp = allhT + (size_t)b * D2H * Tt;
#pragma unroll
  for (int j = 0; j < 4; ++j)
    tile[ty + 8 * j][tx] = in[(size_t)(t0 + ty + 8 * j) * D2H + d0 + tx];
  __syncthreads();
#pragma unroll
  for (int j = 0; j < 4; ++j)
    outp[(size_t)(d0 + ty + 8 * j) * Tt + t0 + tx] = tile[tx][ty + 8 * j];
}

// ---------------- fused g/f GEMM + gating epilogue -> attn (f32) ----------------
__global__ __launch_bounds__(256) void gf_fused(const _Float16* __restrict__ ctx,
                                                const _Float16* __restrict__ allh,
                                                const _Float16* __restrict__ Wgf,
                                                const float* __restrict__ bg,
                                                const float* __restrict__ bfv,
                                                float* __restrict__ out_attn) {
  int m0 = blockIdx.y * 64;
  int cb = blockIdx.x * 32;
  int w = threadIdx.x >> 6, lane = threadIdx.x & 63;
  int nrow = (w >> 1) * 1024 + cb + (w & 1) * 16;  // w0,w1: g cols; w2,w3: f cols

  f32x4 a0 = {0.f,0.f,0.f,0.f}, a1 = a0, a2 = a0, a3 = a0;
  for (int k0 = 0; k0 < 1024; k0 += 32) {   // phase 1: cat[:,0:1024] = ctx
    f16x8 bfr = ldfrag(Wgf, 2048, nrow, k0, lane);
    a0 = __builtin_amdgcn_mfma_f32_16x16x32_f16(ldfrag(ctx, 1024, m0 +  0, k0, lane), bfr, a0, 0,0,0);
    a1 = __builtin_amdgcn_mfma_f32_16x16x32_f16(ldfrag(ctx, 1024, m0 + 16, k0, lane), bfr, a1, 0,0,0);
    a2 = __builtin_amdgcn_mfma_f32_16x16x32_f16(ldfrag(ctx, 1024, m0 + 32, k0, lane), bfr, a2, 0,0,0);
    a3 = __builtin_amdgcn_mfma_f32_16x16x32_f16(ldfrag(ctx, 1024, m0 + 48, k0, lane), bfr, a3, 0,0,0);
  }
  for (int k0 = 0; k0 < 1024; k0 += 32) {   // phase 2: cat[:,1024:2048] = all_h
    f16x8 bfr = ldfrag(Wgf, 2048, nrow, 1024 + k0, lane);
    a0 = __builtin_amdgcn_mfma_f32_16x16x32_f16(ldfrag(allh, 1024, m0 +  0, k0, lane), bfr, a0, 0,0,0);
    a1 = __builtin_amdgcn_mfma_f32_16x16x32_f16(ldfrag(allh, 1024, m0 + 16, k0, lane), bfr, a1, 0,0,0);
    a2 = __builtin_amdgcn_mfma_f32_16x16x32_f16(ldfrag(allh, 1024, m0 + 32, k0, lane), bfr, a2, 0,0,0);
    a3 = __builtin_amdgcn_mfma_f32_16x16x32_f16(ldfrag(allh, 1024, m0 + 48, k0, lane), bfr, a3, 0,0,0);
  }
  int col = lane & 15;
  int n = nrow + col;
  float bv = (n < 1024) ? bg[n] : bfv[n - 1024];

  __shared__ float lds[4][64][16];
  int rbase = 4 * (lane >> 4);
  f32x4 acc[4] = {a0, a1, a2, a3};
#pragma unroll
  for (int mt = 0; mt < 4; ++mt)
#pragma unroll
    for (int r = 0; r < 4; ++r)
      lds[w][mt * 16 + rbase + r][col] = acc[mt][r] + bv;
  __syncthreads();

  for (int e = threadIdx.x; e < 64 * 32; e += 256) {
    int row = e >> 5, c = e & 31;
    float gv = lds[c >> 4][row][c & 15];
    float fv = lds[2 + (c >> 4)][row][c & 15];
    float gg = sigm(gv);
    float ff = tanhf(fv);
    int m = m0 + row, cg = cb + c;
    float ah = (float)allh[(size_t)m * D2H + cg];
    out_attn[(size_t)m * D2H + cg] = gg * ff + (1.0f - gg) * ah;
  }
}

// ---------------- final concat output ----------------
__global__ void write_concat(const float* __restrict__ h1f, const float* __restrict__ h1b,
                             float* __restrict__ out) {
  int i = blockIdx.x * 256 + threadIdx.x;
  if (i >= Bb * D2H) return;
  int b = i >> 10, c = i & 1023;
  out[i] = (c < Hh) ? h1f[b * Hh + c] : h1b[b * Hh + (c - Hh)];
}

// =============================== host ===============================
extern "C" void kernel_launch(void* const* d_in, const int* in_sizes, int n_in,
                              void* d_out, int out_size, void* d_ws, size_t ws_size,
                              hipStream_t stream) {
  const int*   context = (const int*)d_in[0];
  const int*   tags    = (const int*)d_in[1];
  const float* glove   = (const float*)d_in[2];
  const float* bio     = (const float*)d_in[3];
  const float* b_lin   = (const float*)d_in[21];
  const float* b_g     = (const float*)d_in[23];
  const float* b_f     = (const float*)d_in[25];

  char* ws = (char*)d_ws;
  size_t off = 0;
  auto carve = [&](size_t bytes) -> void* {
    void* pp = ws + off;
    off = (off + bytes + 255) & ~(size_t)255;
    return pp;
  };

  _Float16* xt = (_Float16*)carve((size_t)Tt * Bb * INPP * 2);
  _Float16 *Wx16[2][2], *Wh16[2][2];
  Wx16[0][0] = (_Float16*)carve((size_t)1536 * 320 * 2);
  Wx16[1][0] = (_Float16*)carve((size_t)1536 * 320 * 2);
  Wx16[0][1] = (_Float16*)carve((size_t)1536 * 512 * 2);
  Wx16[1][1] = (_Float16*)carve((size_t)1536 * 512 * 2);
  for (int d = 0; d < 2; ++d)
    for (int l = 0; l < 2; ++l) Wh16[d][l] = (_Float16*)carve((size_t)1536 * 512 * 2);
  _Float16* wlin = (_Float16*)carve((size_t)1024 * 1024 * 2);
  _Float16* wgf  = (_Float16*)carve((size_t)2048 * 2048 * 2);
  _Float16* allh  = (_Float16*)carve((size_t)Bb * Tt * D2H * 2);
  _Float16* allhT = (_Float16*)carve((size_t)Bb * Tt * D2H * 2);
  _Float16* qctx  = (_Float16*)carve((size_t)Bb * Tt * D2H * 2);   // q, then reused as ctx
  float*    scores = (float*)carve((size_t)Bb * Tt * Tt * 4);
  _Float16* pmat   = (_Float16*)carve((size_t)Bb * Tt * Tt * 2);
  float*    h32buf = (float*)carve((size_t)2 * 2 * 2 * Bb * Hh * 4);
  _Float16* h16buf = (_Float16*)carve((size_t)2 * 2 * 2 * Bb * Hh * 2);

  // zero recurrent state (both slots)
  hipMemsetAsync(h32buf, 0, (size_t)2 * 2 * 2 * Bb * Hh * 4, stream);
  hipMemsetAsync(h16buf, 0, (size_t)2 * 2 * 2 * Bb * Hh * 2, stream);

  auto conv = [&](const void* src, _Float16* dst, int rows, int csrc, int cdst) {
    int total = rows * cdst;
    convert_pad<<<(total + 255) / 256, 256, 0, stream>>>((const float*)src, dst, rows, csrc, cdst);
  };
  conv(d_in[4],  Wx16[0][0], 1536, 303, 320);
  conv(d_in[12], Wx16[1][0], 1536, 303, 320);
  conv(d_in[8],  Wx16[0][1], 1536, 512, 512);
  conv(d_in[16], Wx16[1][1], 1536, 512, 512);
  conv(d_in[5],  Wh16[0][0], 1536, 512, 512);
  conv(d_in[13], Wh16[1][0], 1536, 512, 512);
  conv(d_in[9],  Wh16[0][1], 1536, 512, 512);
  conv(d_in[17], Wh16[1][1], 1536, 512, 512);
  conv(d_in[20], wlin, 1024, 1024, 1024);
  conv(d_in[22], wgf, 1024, 2048, 2048);
  conv(d_in[24], wgf + (size_t)1024 * 2048, 1024, 2048, 2048);

  embed_kernel<<<Tt * Bb, 64, 0, stream>>>(context, tags, glove, bio, xt);

  GruParams GP;
  GP.xt = xt;
  GP.Wx[0][0] = Wx16[0][0]; GP.Wx[0][1] = Wx16[0][1]; GP.Wx[1][0] = Wx16[1][0]; GP.Wx[1][1] = Wx16[1][1];
  GP.Wh[0][0] = Wh16[0][0]; GP.Wh[0][1] = Wh16[0][1]; GP.Wh[1][0] = Wh16[1][0]; GP.Wh[1][1] = Wh16[1][1];
  GP.bih[0][0] = (const float*)d_in[6];  GP.bhh[0][0] = (const float*)d_in[7];
  GP.bih[0][1] = (const float*)d_in[10]; GP.bhh[0][1] = (const float*)d_in[11];
  GP.bih[1][0] = (const float*)d_in[14]; GP.bhh[1][0] = (const float*)d_in[15];
  GP.bih[1][1] = (const float*)d_in[18]; GP.bhh[1][1] = (const float*)d_in[19];
  for (int d = 0; d < 2; ++d)
    for (int l = 0; l < 2; ++l) {
      GP.h32[d][l] = h32buf + (size_t)((d * 2 + l) * 2) * Bb * Hh;
      GP.h16[d][l] = h16buf + (size_t)((d * 2 + l) * 2) * Bb * Hh;
    }
  GP.allh = allh;

  for (int s = 0; s <= Tt; ++s)
    gru_step<<<128, 256, 0, stream>>>(GP, s);

  // q = all_h @ W_lin^T + b_lin  -> f16
  GemmArgs ga;
  ga.A = allh; ga.lda = 1024; ga.sAz = 0;
  ga.Bm = wlin; ga.ldb = 1024; ga.sBz = 0;
  ga.bias = b_lin; ga.Cf = nullptr; ga.Ch = qctx; ga.ldc = 1024; ga.sCz = 0; ga.K = 1024;
  gemm_tn<<<dim3(16, 512, 1), 256, 0, stream>>>(ga);

  // scores[b] = q[b] @ all_h[b]^T -> f32
  ga.A = qctx; ga.lda = 1024; ga.sAz = (long long)512 * 1024;
  ga.Bm = allh; ga.ldb = 1024; ga.sBz = (long long)512 * 1024;
  ga.bias = nullptr; ga.Cf = scores; ga.Ch = nullptr; ga.ldc = 512; ga.sCz = (long long)512 * 512; ga.K = 1024;
  gemm_tn<<<dim3(8, 8, 64), 256, 0, stream>>>(ga);

  softmax_rows<<<(Bb * Tt) / 4, 256, 0, stream>>>(scores, pmat);

  transpose_bt<<<dim3(32, 16, 64), dim3(32, 8), 0, stream>>>(allh, allhT);

  // ctx[b] = p[b] @ (all_hT[b])^T  -> f16 (overwrites q)
  ga.A = pmat; ga.lda = 512; ga.sAz = (long long)512 * 512;
  ga.Bm = allhT; ga.ldb = 512; ga.sBz = (long long)1024 * 512;
  ga.bias = nullptr; ga.Cf = nullptr; ga.Ch = qctx; ga.ldc = 1024; ga.sCz = (long long)512 * 1024; ga.K = 512;
  gemm_tn<<<dim3(16, 8, 64), 256, 0, stream>>>(ga);

  float* out_attn = (float*)d_out + (size_t)Bb * D2H;
  gf_fused<<<dim3(32, 512), 256, 0, stream>>>(qctx, allh, wgf, b_g, b_f, out_attn);

  const float* h1f_fin = h32buf + (size_t)((0 * 2 + 0) * 2 + 1) * Bb * Hh;  // dir 0, layer 0, slot 1 (t=511)
  const float* h1b_fin = h32buf + (size_t)((1 * 2 + 0) * 2 + 1) * Bb * Hh;
  write_concat<<<(Bb * D2H + 255) / 256, 256, 0, stream>>>(h1f_fin, h1b_fin, (float*)d_out);
}